// Round 9
// baseline (100.686 us; speedup 1.0000x reference)
//
#include <hip/hip_runtime.h>
#include <hip/hip_bf16.h>

#define BB 64
#define NN 96
#define FF 16
#define HH 128
#define KK 64
#define LL 3
#define CUTOFF_F 10.0f
#define GAMMA_F 10.0f

#define WT_BLOCKS 99          // 3 layers * 33 blocks (2 rows of W3 each, 65 rows/layer)
#define CNT_BLOCKS BB

// ---------------------------------------------------------------------------
// pre_kernel:
//   [0,99):   rows {2i,2i+1} of W2[l]=Wrbf@Wpair (row 64 = bias row) staged in
//             LDS, then W3 rows = W2row@Wa1 (row 64 -> c3).
//   [99,163): cnt[b] = #valid atoms; zero out[b] (atomic target in chain)
// ---------------------------------------------------------------------------
__global__ __launch_bounds__(256) void pre_kernel(
    const float* __restrict__ Wrbf, const float* __restrict__ brbf,
    const float* __restrict__ Wpair, const float* __restrict__ bpair,
    const float* __restrict__ Wa1,
    const int* __restrict__ batch,
    float* __restrict__ W3, float* __restrict__ c3,
    float* __restrict__ cnt, float* __restrict__ out)
{
    const int bid = blockIdx.x;
    const int tid = threadIdx.x;
    if (bid < WT_BLOCKS) {
        __shared__ float sW2[2][HH];
        const int l    = bid / 33;
        const int r0   = (bid % 33) * 2;
        const int half = tid >> 7;
        const int h    = tid & 127;
        const int kk   = r0 + half;       // 0..65 (65 inactive)
        const bool active = (kk <= KK);
        if (active) {
            const float* Wp = Wpair + l * HH * HH + h;
            const float* arow;
            float acc;
            if (kk < KK) { arow = Wrbf + (l * KK + kk) * HH; acc = 0.f; }
            else         { arow = brbf + l * HH;             acc = bpair[l * HH + h]; }
            #pragma unroll 8
            for (int m = 0; m < HH; ++m) acc += arow[m] * Wp[m * HH];
            sW2[half][h] = acc;
        }
        __syncthreads();
        if (active) {
            const float* Wa = Wa1 + l * HH * HH + h;
            const float* row = sW2[half];
            float a3 = 0.f;
            #pragma unroll 8
            for (int m = 0; m < HH; ++m) a3 += row[m] * Wa[m * HH];
            if (kk < KK) W3[(l * KK + kk) * HH + h] = a3;
            else         c3[l * HH + h] = a3;
        }
    } else {
        int b = bid - WT_BLOCKS;
        __shared__ int c[4];
        bool v = (tid < NN) && (batch[b * NN + tid] != -1);
        unsigned long long m = __ballot(v);
        if ((tid & 63) == 0) c[tid >> 6] = __popcll(m);
        __syncthreads();
        if (tid == 0) {
            cnt[b] = (float)(c[0] + c[1] + c[2] + c[3]);
            out[b] = 0.f;                 // zero the atomic target each call
        }
    }
}

// ---------------------------------------------------------------------------
// chain_kernel: fused S-compute + per-atom MLP chain.
// Block = 512 threads (8 waves), AT=12 atoms, grid 512 = 2 blocks/CU
// -> 16 waves/CU = 4 waves/SIMD (latency hiding via TLP).
// Thread tile: 1 channel x 3 atoms. hh=tid&127 (channel), g=tid>>7 (atom
// triple: atoms 3g..3g+2 at LDS cols 4g..4g+2, col 4g+3 is pad).
// Per GEMM k-step: 1 coalesced global weight scalar + 1 broadcast
// ds_read_b128 -> 3 FMAs. Weights stream from L2 (read once per block).
// ---------------------------------------------------------------------------
#define AT 12
#define SSW 16   // 4 atom-groups * 4 cols (3 atoms + pad)

__device__ __forceinline__ float silu1(float v) { return v / (1.f + __expf(-v)); }

__global__ __launch_bounds__(512, 4) void chain_kernel(
    const float* __restrict__ X, const float* __restrict__ R,
    const float* __restrict__ We, const float* __restrict__ be,
    const float* __restrict__ ba1, const float* __restrict__ Wa2,
    const float* __restrict__ ba2, const float* __restrict__ Wo1,
    const float* __restrict__ bo1, const float* __restrict__ Wo2,
    const float* __restrict__ bo2, const float* __restrict__ W3,
    const float* __restrict__ c3, const float* __restrict__ cnt,
    float* __restrict__ out)
{
    __shared__ __align__(16) float sS[KK][SSW];   // 4 KB (S^T, persists)
    __shared__ __align__(16) float tb[HH][SSW];   // 8 KB (t / h staging; sD+sRf early)
    __shared__ __align__(16) float sX[FF][SSW];   // 1 KB
    __shared__ float po[8][AT];

    const int tid = threadIdx.x;
    const int hh  = tid & 127;           // channel
    const int g   = tid >> 7;            // atom triple 0..3
    const int wv  = tid >> 6;            // wave 0..7
    const int g4  = g * 4;
    const int a0  = blockIdx.x * AT;     // 96 % 12 == 0 -> block within one molecule
    const int b   = a0 / NN;
    const int lbase = a0 - b * NN;       // molecule-local first atom
    const float cb = cnt[b];
    const int nv  = (int)cb;             // valid atoms are prefix 0..nv-1 (local)

    // scratch aliased into tb (dead before first tb write)
    float* sD  = &tb[0][0];              // AT*NN = 1152 floats: distances
    float* sRf = sD + AT * NN;           // 288 floats: molecule R

    // ---- stage molecule R, X^T ----
    if (tid < NN * 3) sRf[tid] = R[b * NN * 3 + tid];
    if (tid < AT * FF) {
        int a = tid >> 4, f = tid & 15;
        sX[f][(a / 3) * 4 + a % 3] = X[(a0 + a) * FF + f];
    }
    __syncthreads();

    // ---- phase 1: distance table D[j][i] ----
    for (int e = tid; e < AT * NN; e += 512) {
        int j = e / NN, i = e - j * NN;
        float dx = sRf[i * 3 + 0] - sRf[(lbase + j) * 3 + 0];
        float dy = sRf[i * 3 + 1] - sRf[(lbase + j) * 3 + 1];
        float dz = sRf[i * 3 + 2] - sRf[(lbase + j) * 3 + 2];
        sD[e] = sqrtf(dx * dx + dy * dy + dz * dz);
    }
    __syncthreads();

    // ---- phase 2: sS[k][col(j)] = sum_{i<nv} exp(-g*(D[j][i]-ck)^2) ----
    // waves 0..3 handle rows {wv, wv+8}; waves 4..7 handle row {wv}
    {
        const int k  = tid & 63;
        const float ck = (float)k * (CUTOFF_F / (float)(KK - 1));
        const int nrows = (wv < 4) ? 2 : 1;
        for (int r = 0; r < nrows; ++r) {
            int j = wv + r * 8;          // wave-uniform
            int col = (j / 3) * 4 + j % 3;
            if (lbase + j >= nv) { sS[k][col] = 0.f; continue; }
            const float* Dr = sD + j * NN;
            float acc = 0.f;
            for (int i = 0; i < nv; ++i) {
                float u = Dr[i] - ck;
                acc += __expf(-GAMMA_F * u * u);
            }
            sS[k][col] = acc;
        }
    }

    // ---- embedding: h = X@We + be (reads sX only) ----
    float h[3];
    {
        float acc[3] = {0, 0, 0};
        const float* wp = We + hh;
        #pragma unroll
        for (int f = 0; f < FF; ++f) {
            float w = wp[f * HH];
            float4 x4 = *(const float4*)&sX[f][g4];
            acc[0] += w * x4.x; acc[1] += w * x4.y; acc[2] += w * x4.z;
        }
        float bee = be[hh];
        h[0] = acc[0] + bee; h[1] = acc[1] + bee; h[2] = acc[2] + bee;
    }

    __syncthreads();   // S0: sS visible; sD/sRf dead

    // ---- layers ----
    for (int l = 0; l < LL; ++l) {
        // GEMM1: acc = S @ W3[l]  (weights global/L2, atoms LDS broadcast)
        float acc[3] = {0, 0, 0};
        {
            const float* wp = W3 + l * KK * HH + hh;
            #pragma unroll 16
            for (int k = 0; k < KK; ++k) {
                float w = wp[k * HH];
                float4 t4 = *(const float4*)&sS[k][g4];
                acc[0] += w * t4.x; acc[1] += w * t4.y; acc[2] += w * t4.z;
            }
        }
        float biasv = cb * c3[l * HH + hh] + ba1[l * HH + hh];
        float t0 = silu1(acc[0] + biasv);
        float t1 = silu1(acc[1] + biasv);
        float t2 = silu1(acc[2] + biasv);

        __syncthreads();   // S1: previous tb readers done
        tb[hh][g4 + 0] = t0;
        tb[hh][g4 + 1] = t1;
        tb[hh][g4 + 2] = t2;
        __syncthreads();   // S2: tb visible

        // GEMM2: h += t @ Wa2[l]
        float acc2[3] = {0, 0, 0};
        {
            const float* wq = Wa2 + l * HH * HH + hh;
            #pragma unroll 16
            for (int m = 0; m < HH; ++m) {
                float w = wq[m * HH];
                float4 t4 = *(const float4*)&tb[m][g4];
                acc2[0] += w * t4.x; acc2[1] += w * t4.y; acc2[2] += w * t4.z;
            }
        }
        float b2 = ba2[l * HH + hh];
        h[0] += acc2[0] + b2; h[1] += acc2[1] + b2; h[2] += acc2[2] + b2;
    }

    // ---- output head ----
    __syncthreads();   // S3: prior tb readers done
    tb[hh][g4 + 0] = h[0];
    tb[hh][g4 + 1] = h[1];
    tb[hh][g4 + 2] = h[2];
    __syncthreads();   // S4: tb visible

    float acc[3] = {0, 0, 0};
    {
        const float* wp = Wo1 + hh;
        #pragma unroll 16
        for (int m = 0; m < HH; ++m) {
            float w = wp[m * HH];
            float4 t4 = *(const float4*)&tb[m][g4];
            acc[0] += w * t4.x; acc[1] += w * t4.y; acc[2] += w * t4.z;
        }
    }
    float bo = bo1[hh], wo2v = Wo2[hh];
    float p[3];
    #pragma unroll
    for (int a = 0; a < 3; ++a) p[a] = silu1(acc[a] + bo) * wo2v;

    // reduce across the 64 channel-lanes of each wave
    #pragma unroll
    for (int a = 0; a < 3; ++a) {
        float r = p[a];
        r += __shfl_down(r, 32); r += __shfl_down(r, 16);
        r += __shfl_down(r, 8);  r += __shfl_down(r, 4);
        r += __shfl_down(r, 2);  r += __shfl_down(r, 1);
        p[a] = r;
    }
    if ((tid & 63) == 0) {
        #pragma unroll
        for (int a = 0; a < 3; ++a) po[wv][3 * g + a] = p[a];
    }
    __syncthreads();
    if (tid == 0) {
        float bo2v = bo2[0];
        float sum = 0.f;
        #pragma unroll
        for (int j = 0; j < AT; ++j) {
            if (lbase + j < nv) {
                int gg = j / 3;
                sum += po[2 * gg][j % 3 + 3 * gg - 3 * gg]  // placeholder removed below
                     ;
            }
        }
        // recompute cleanly: atom j handled by waves 2*(j/3) and 2*(j/3)+1
        sum = 0.f;
        #pragma unroll
        for (int j = 0; j < AT; ++j) {
            if (lbase + j < nv) {
                int gg = j / 3;
                sum += po[2 * gg][j] + po[2 * gg + 1][j] + bo2v;
            }
        }
        atomicAdd(out + b, sum / cb);
    }
}

extern "C" void kernel_launch(void* const* d_in, const int* in_sizes, int n_in,
                              void* d_out, int out_size, void* d_ws, size_t ws_size,
                              hipStream_t stream) {
    const float* X     = (const float*)d_in[0];
    const float* R     = (const float*)d_in[1];
    const int*   batch = (const int*)  d_in[2];
    const float* We    = (const float*)d_in[3];
    const float* be    = (const float*)d_in[4];
    const float* Wrbf  = (const float*)d_in[5];
    const float* brbf  = (const float*)d_in[6];
    const float* Wpair = (const float*)d_in[7];
    const float* bpair = (const float*)d_in[8];
    const float* Wa1   = (const float*)d_in[9];
    const float* ba1   = (const float*)d_in[10];
    const float* Wa2   = (const float*)d_in[11];
    const float* ba2   = (const float*)d_in[12];
    const float* Wo1   = (const float*)d_in[13];
    const float* bo1   = (const float*)d_in[14];
    const float* Wo2   = (const float*)d_in[15];
    const float* bo2   = (const float*)d_in[16];

    float* w   = (float*)d_ws;
    float* W3  = w;                        // L*K*H = 24576
    float* c3  = W3 + LL * KK * HH;        // L*H   = 384
    float* cnt = c3 + LL * HH;             // B     = 64
    float* out = (float*)d_out;

    hipLaunchKernelGGL(pre_kernel, dim3(WT_BLOCKS + CNT_BLOCKS), dim3(256),
                       0, stream, Wrbf, brbf, Wpair, bpair, Wa1, batch,
                       W3, c3, cnt, out);
    hipLaunchKernelGGL(chain_kernel, dim3(BB * NN / AT), dim3(512), 0, stream,
                       X, R, We, be, ba1, Wa2, ba2, Wo1, bo1, Wo2, bo2,
                       W3, c3, cnt, out);
}